// Round 8
// baseline (288.493 us; speedup 1.0000x reference)
//
#include <hip/hip_runtime.h>
#include <cstdint>
#include <type_traits>

typedef unsigned short u16;
typedef unsigned int u32;
typedef __bf16 bf16x8 __attribute__((ext_vector_type(8)));
typedef float f32x4 __attribute__((ext_vector_type(4)));

constexpr int BB = 2;
constexpr int SEQ = 2048;
constexpr int CH = 2048;
constexpr int NH = 16;
constexpr int NKV = 4;
constexpr int HD = 128;
constexpr int QKVC = CH + 2 * NKV * HD;  // 3072

#define DI __device__ __forceinline__

DI u16 f2b(float x) {  // fp32 -> bf16 bits, RNE
  u32 u = __float_as_uint(x);
  u = u + 0x7FFFu + ((u >> 16) & 1u);
  return (u16)(u >> 16);
}
DI float b2f(u16 u) { return __uint_as_float(((u32)u) << 16); }

// pack two fp32 -> two bf16 (truncating) in ONE v_perm_b32
DI u32 pack2bf(float lo, float hi) {
  return __builtin_amdgcn_perm(__float_as_uint(hi), __float_as_uint(lo), 0x07060302u);
}

// async global->LDS, 16B per lane. LDS dest is wave-uniform base + lane*16.
DI void glds16(const void* g, void* l) {
  __builtin_amdgcn_global_load_lds(
      (__attribute__((address_space(1))) void*)(uintptr_t)g,
      (__attribute__((address_space(3))) void*)(u32)(uintptr_t)l, 16, 0, 0);
}

// -------- fused prep: xconv (z==4, grid-stride) + wtrans4 (z<4) --------
__global__ __launch_bounds__(256) void prep_kernel(
    const float* __restrict__ x, u16* __restrict__ xb,
    const float* __restrict__ Wq, const float* __restrict__ Wk,
    const float* __restrict__ Wv, const float* __restrict__ Wo,
    u16* __restrict__ wqkvt, u16* __restrict__ wot) {
  if (blockIdx.z == 4) {  // ---- xconv: fp32 x -> bf16, 2M float4s ----
    const int n4 = BB * SEQ * CH / 4;
    int base = (blockIdx.x + 32 * blockIdx.y) * 256 + threadIdx.x;
#pragma unroll
    for (int k = 0; k < 8; k++) {
      int i = base + k * 262144;
      if (i < n4) {
        float4 v = *(const float4*)&x[(size_t)i * 4];
        ushort4 o;
        o.x = f2b(v.x); o.y = f2b(v.y); o.z = f2b(v.z); o.w = f2b(v.w);
        *(ushort4*)&xb[(size_t)i * 4] = o;
      }
    }
    return;
  }
  // ---- wtrans4: transpose-convert weight slice z ----
  const int z = blockIdx.z;
  const float* in;
  u16* out;
  int Cc;
  if (z == 0)      { in = Wq; out = wqkvt;                                Cc = CH; }
  else if (z == 1) { in = Wk; out = wqkvt + (size_t)CH * CH;              Cc = NKV * HD; }
  else if (z == 2) { in = Wv; out = wqkvt + (size_t)(CH + NKV * HD) * CH; Cc = NKV * HD; }
  else             { in = Wo; out = wot;                                  Cc = CH; }
  if ((int)blockIdx.y * 64 >= Cc) return;

  __shared__ u16 tile[64 * 65];
  const int r0 = blockIdx.x * 64, c0 = blockIdx.y * 64;
  const int tid = threadIdx.x;
  for (int c = tid; c < 1024; c += 256) {
    int r = c >> 4, col = (c & 15) * 4;
    float4 v = *(const float4*)&in[(size_t)(r0 + r) * Cc + c0 + col];
    tile[r * 65 + col + 0] = f2b(v.x);
    tile[r * 65 + col + 1] = f2b(v.y);
    tile[r * 65 + col + 2] = f2b(v.z);
    tile[r * 65 + col + 3] = f2b(v.w);
  }
  __syncthreads();
  for (int c = tid; c < 1024; c += 256) {
    int r = c >> 4, col = (c & 15) * 4;
    ushort4 v;
    v.x = tile[(col + 0) * 65 + r];
    v.y = tile[(col + 1) * 65 + r];
    v.z = tile[(col + 2) * 65 + r];
    v.w = tile[(col + 3) * 65 + r];
    *(ushort4*)&out[(size_t)(c0 + r) * CH + r0 + col] = v;
  }
}

// ------------- transpose bf16 V (SEQ x HD slices) -> V^T (HD x SEQ) -------------
__global__ __launch_bounds__(256) void vtrans_kernel(const u16* __restrict__ in,
                                                     u16* __restrict__ out) {
  __shared__ u16 tile[64 * 65];
  const int s = blockIdx.z, n0 = blockIdx.x * 64, d0 = blockIdx.y * 64;
  const int tid = threadIdx.x;
  const u16* ip = in + (size_t)s * SEQ * HD + (size_t)n0 * HD + d0;
  u16* op = out + (size_t)s * HD * SEQ + (size_t)d0 * SEQ + n0;
  for (int c = tid; c < 1024; c += 256) {
    int r = c >> 4, col = (c & 15) * 4;
    ushort4 v = *(const ushort4*)&ip[(size_t)r * HD + col];
    tile[r * 65 + col + 0] = v.x;
    tile[r * 65 + col + 1] = v.y;
    tile[r * 65 + col + 2] = v.z;
    tile[r * 65 + col + 3] = v.w;
  }
  __syncthreads();
  for (int c = tid; c < 1024; c += 256) {
    int r = c >> 4, col = (c & 15) * 4;  // r = local d, col = local n (u), u&3==0
    ushort4 v;
    v.x = tile[(col + 0) * 65 + r];
    v.y = tile[(col + 1) * 65 + r];
    v.z = tile[(col + 2) * 65 + r];
    v.w = tile[(col + 3) * 65 + r];
    int u = col;
    int w = (u & 3) | (((u >> 5) & 1) << 2) | (((u >> 2) & 3) << 3) | (((u >> 4) & 1) << 5);
    int glp = (w >> 3) ^ (r & 7);
    int colp = glp * 8 + (w & 7);
    *(ushort4*)&op[(size_t)r * SEQ + colp] = v;
  }
}

// ------------- bf16 MFMA GEMM, 4-wave blocks, 2 blocks/CU, rolling LDS ---------------
// Cross-block overlap experiment: R1-R7's 8-wave/128KB-LDS GEMMs pin at ~73us because
// one block/CU leaves no independent work across barriers. Here: 4 waves (2Mx2N),
// 512 blocks = 2 blocks/CU -> two independent barrier domains per CU.
// MODE 0 (x@Wqkv + bias + fused RoPE): BM=128 BN=192, grid (32,16). Wave 64x96,
//   acc[4][6], 3 phases x 16 MFMA. FULLY-ROLLING LDS (40KB: A[128][64] + B[192][64],
//   single copies; region restaged right after its consuming phase):
//     issue slots: B2(T)@q0, A(T+1)+B0(T+1)@q1, B1(T+1)@q2 (uniform 2-phase flight)
//     FIFO waits:  vmcnt(2)@q0-end (drain B1(T)), vmcnt(6)@q1-end (drain B2(T)),
//                  vmcnt(2)@q2-end (drain A'+B0'). Never 0 except tail.
//   B rows consumption-permuted: LDS row l = 64q + wcol*32 + c <-> global 96*wcol+32q+c.
//   LDS alloc 64KB (epilogue f32 cos/sin table reuse) -> 2 resident/CU.
// MODE 1 (ao@Wo, f32 out): BM=128 BN=128, grid (32,16). Wave 64x64, acc[4][4],
//   2 phases x 16 MFMA. Rolling-A + dbuf-B = 48KB. Slots: B0(T+1)@q0, A(T+1)+B1(T+1)@q1;
//   uniform vmcnt(2) waits (prologue issue order B0,A,B1 preserves FIFO).
// Swizzle: 16B slot s of LDS row l holds global col-group s^(l&7); staging rr=tid>>3
// gives l&7==rr&7; readers use lm&7. glds16 dest = wave-uniform base + lane*16.
template <int MODE>
__global__ __launch_bounds__(256, 2) void gemm4w_kernel(
    const u16* __restrict__ A, const u16* __restrict__ Bt,
    u16* __restrict__ Qo, u16* __restrict__ Ko,
    float* __restrict__ Cf, u16* __restrict__ Vn,
    const float* __restrict__ bq, const float* __restrict__ bk,
    const float* __restrict__ bv, const int* __restrict__ pos,
    int M, int Nn, int K) {
  constexpr int BM = 128;
  constexpr int BN = (MODE == 0) ? 192 : 128;
  constexpr int NJ = (MODE == 0) ? 6 : 4;   // N-frags per wave
  extern __shared__ char smem[];
  u16* As = (u16*)smem;            // [128][64] rolling
  u16* Bs = As + 128 * 64;         // MODE0: [192][64] rolling; MODE1: [2][128][64] dbuf

  const int tid = threadIdx.x;
  const int lane = tid & 63, wave = tid >> 6;
  const int wrow = wave >> 1, wcol = wave & 1;
  const int lm = lane & 15, lq = lane >> 4;
  const int m0 = blockIdx.x * BM, n0 = blockIdx.y * BN;
  const int rr = tid >> 3;                       // staging row 0..31 per call
  const int sswz8 = ((tid & 7) ^ (rr & 7)) * 8;  // swizzled global col-group

  f32x4 acc[4][NJ] = {};
  const int NT = K >> 6;

  // stage one 32-row unit (4KB): LDS rows [32s, 32s+32); wave covers rows 32s+wave*8..+8
  auto stA = [&](int kt, int s) {
    glds16(A + (size_t)(m0 + 32 * s + rr) * K + kt + sswz8,
           (char*)As + (32 * s + wave * 8) * 128);
  };
  auto stB = [&](int kt, int s, int bsel) {
    int g0 = (MODE == 0) ? (96 * (s & 1) + 32 * (s >> 1))
                         : (64 * (s & 1) + 32 * (s >> 1));
    glds16(Bt + (size_t)(n0 + g0 + rr) * K + kt + sswz8,
           (char*)Bs + bsel * 16384 + (32 * s + wave * 8) * 128);
  };

  if constexpr (MODE == 0) {
    // prologue: A(0) x4, B0(0) x2, B1(0) x2  -> drain A+B0 (leave B1)
    stA(0, 0); stA(0, 1); stA(0, 2); stA(0, 3);
    stB(0, 0, 0); stB(0, 1, 0);
    stB(0, 2, 0); stB(0, 3, 0);
    asm volatile("s_waitcnt vmcnt(2)" ::: "memory");
    __builtin_amdgcn_s_barrier();

    bf16x8 af[4][2];
    for (int T = 0; T < NT; T++) {
      const int kt = T << 6, kt1 = (T + 1) << 6;
      const bool pf = (T + 1 < NT);
#pragma unroll
      for (int q = 0; q < 3; q++) {
        if (q == 0) {
#pragma unroll
          for (int ii = 0; ii < 4; ii++)
#pragma unroll
            for (int kk = 0; kk < 2; kk++)
              af[ii][kk] = *(const bf16x8*)&As[(wrow * 64 + ii * 16 + lm) * 64 +
                                               ((kk * 4 + lq) ^ (lm & 7)) * 8];
        }
        bf16x8 bfq[2][2];
#pragma unroll
        for (int jj = 0; jj < 2; jj++)
#pragma unroll
          for (int kk = 0; kk < 2; kk++)
            bfq[jj][kk] = *(const bf16x8*)&Bs[(64 * q + wcol * 32 + jj * 16 + lm) * 64 +
                                              ((kk * 4 + lq) ^ (lm & 7)) * 8];
        // issue slots (regions freed by the barrier pair that ended the prior phase)
        if (q == 0) { stB(kt, 4, 0); stB(kt, 5, 0); }  // B2(T): needed q2(T), 2-phase flight
        else if (q == 1 && pf) { stA(kt1, 0); stA(kt1, 1); stA(kt1, 2); stA(kt1, 3);
                                 stB(kt1, 0, 0); stB(kt1, 1, 0); }  // A', B0'
        else if (q == 2 && pf) { stB(kt1, 2, 0); stB(kt1, 3, 0); }  // B1'
        __builtin_amdgcn_s_barrier();
        asm volatile("s_waitcnt lgkmcnt(0)" ::: "memory");
        __builtin_amdgcn_sched_barrier(0);
        __builtin_amdgcn_s_setprio(1);
#pragma unroll
        for (int kk = 0; kk < 2; kk++)
#pragma unroll
          for (int ii = 0; ii < 4; ii++)
#pragma unroll
            for (int jj = 0; jj < 2; jj++)
              acc[ii][q * 2 + jj] = __builtin_amdgcn_mfma_f32_16x16x32_bf16(
                  af[ii][kk], bfq[jj][kk], acc[ii][q * 2 + jj], 0, 0, 0);
        __builtin_amdgcn_s_setprio(0);
        // counted waits (FIFO: [B1(T),B2(T)] -> [B2,A',B0'] -> [A',B0',B1'])
        if (q == 0) {
          asm volatile("s_waitcnt vmcnt(2)" ::: "memory");           // drain B1(T)
        } else if (q == 1) {
          if (pf) asm volatile("s_waitcnt vmcnt(6)" ::: "memory");   // drain B2(T)
          else    asm volatile("s_waitcnt vmcnt(0)" ::: "memory");
        } else if (pf) {
          asm volatile("s_waitcnt vmcnt(2)" ::: "memory");           // drain A'+B0'
        }
        __builtin_amdgcn_s_barrier();
      }
    }
  } else {
    // prologue (FIFO order matters): B0(0), A(0), B1(0) -> drain B0+A (leave B1)
    stB(0, 0, 0); stB(0, 1, 0);
    stA(0, 0); stA(0, 1); stA(0, 2); stA(0, 3);
    stB(0, 2, 0); stB(0, 3, 0);
    asm volatile("s_waitcnt vmcnt(2)" ::: "memory");
    __builtin_amdgcn_s_barrier();

    bf16x8 af[4][2];
    for (int T = 0; T < NT; T++) {
      const int bsel = T & 1, nbs = bsel ^ 1;
      const int kt1 = (T + 1) << 6;
      const bool pf = (T + 1 < NT);
#pragma unroll
      for (int q = 0; q < 2; q++) {
        if (q == 0) {
#pragma unroll
          for (int ii = 0; ii < 4; ii++)
#pragma unroll
            for (int kk = 0; kk < 2; kk++)
              af[ii][kk] = *(const bf16x8*)&As[(wrow * 64 + ii * 16 + lm) * 64 +
                                               ((kk * 4 + lq) ^ (lm & 7)) * 8];
        }
        bf16x8 bfq[2][2];
#pragma unroll
        for (int jj = 0; jj < 2; jj++)
#pragma unroll
          for (int kk = 0; kk < 2; kk++)
            bfq[jj][kk] = *(const bf16x8*)&Bs[bsel * 8192 +
                                              (64 * q + wcol * 32 + jj * 16 + lm) * 64 +
                                              ((kk * 4 + lq) ^ (lm & 7)) * 8];
        if (q == 0) {
          if (pf) { stB(kt1, 0, nbs); stB(kt1, 1, nbs); }  // B0(T+1) -> other buf
        } else if (pf) {
          stA(kt1, 0); stA(kt1, 1); stA(kt1, 2); stA(kt1, 3);  // A(T+1) (rolling)
          stB(kt1, 2, nbs); stB(kt1, 3, nbs);                  // B1(T+1)
        }
        __builtin_amdgcn_s_barrier();
        asm volatile("s_waitcnt lgkmcnt(0)" ::: "memory");
        __builtin_amdgcn_sched_barrier(0);
        __builtin_amdgcn_s_setprio(1);
#pragma unroll
        for (int kk = 0; kk < 2; kk++)
#pragma unroll
          for (int ii = 0; ii < 4; ii++)
#pragma unroll
            for (int jj = 0; jj < 2; jj++)
              acc[ii][q * 2 + jj] = __builtin_amdgcn_mfma_f32_16x16x32_bf16(
                  af[ii][kk], bfq[jj][kk], acc[ii][q * 2 + jj], 0, 0, 0);
        __builtin_amdgcn_s_setprio(0);
        if (q == 0) {
          if (pf) asm volatile("s_waitcnt vmcnt(2)" ::: "memory");   // drain B1(T)
          else    asm volatile("s_waitcnt vmcnt(0)" ::: "memory");
        } else if (pf) {
          asm volatile("s_waitcnt vmcnt(2)" ::: "memory");           // drain B0'+A'
        }
        __builtin_amdgcn_s_barrier();
      }
    }
  }

  if constexpr (MODE == 0) {
    // ---- build 128x64 cos/sin table in the (dead) LDS (64KB alloc) ----
    __syncthreads();
    float2* tab = (float2*)smem;  // [128][64]
    const float LN1E4_64 = 0.14391156831212788f;  // ln(10000)/64
    for (int e = tid; e < 128 * 64; e += 256) {
      int tk = e >> 6, ii = e & 63;
      float ang = (float)pos[m0 + tk] * expf(-(float)ii * LN1E4_64);
      float sn, cs;
      sincosf(ang, &sn, &cs);
      tab[e] = make_float2(cs, sn);
    }
    __syncthreads();
    const float SCL2G = 0.12754325f;  // (1/sqrt(128)) * log2(e) -- folded into Q

#pragma unroll
    for (int i = 0; i < 4; i++) {
      const int mg = m0 + wrow * 64 + i * 16 + lq * 4;
#pragma unroll
      for (int j = 0; j < NJ; j++) {
        const int ng = n0 + wcol * 96 + j * 16 + lm;
        const int reg7 = (n0 + wcol * 96 + j * 16) >> 7;  // wave-uniform region
        float bias = (ng < CH) ? bq[ng]
                               : (ng < CH + NKV * HD ? bk[ng - CH] : bv[ng - CH - NKV * HD]);
        if (reg7 < 16) {  // ---- Q + rope (SCL2-scaled) ----
          const int d = ng & 127, ii = d >> 1, hh = ng >> 7;
#pragma unroll
          for (int r = 0; r < 4; r++) {
            float v = acc[i][j][r] + bias;
            float vp = __shfl_xor(v, 1);
            float2 cw = tab[(mg + r - m0) * 64 + ii];
            float c = cw.x * SCL2G, s = cw.y * SCL2G;
            float o = fmaf(v, c, (lane & 1) ? vp * s : -(vp * s));
            int tok = mg + r, bb2 = tok >> 11, n = tok & (SEQ - 1);
            Qo[((size_t)(bb2 * NH + hh) * SEQ + n) * HD + d] = f2b(o);
          }
        } else if (reg7 < 20) {  // ---- K + rope, swizzled store ----
          const int d = ng & 127, ii = d >> 1, kh = (ng >> 7) - 16, g = d >> 3;
#pragma unroll
          for (int r = 0; r < 4; r++) {
            float v = acc[i][j][r] + bias;
            float vp = __shfl_xor(v, 1);
            float2 cw = tab[(mg + r - m0) * 64 + ii];
            float o = fmaf(v, cw.x, (lane & 1) ? vp * cw.y : -(vp * cw.y));
            int tok = mg + r, bb2 = tok >> 11, n = tok & (SEQ - 1);
            int gp = (g & 8) | ((g ^ n) & 7);
            Ko[((size_t)(bb2 * NKV + kh) * SEQ + n) * HD + gp * 8 + (d & 7)] = f2b(o);
          }
        } else {  // ---- V: route straight to (b,kv,n,d) layout ----
          const int vcol = ng - (CH + NKV * HD), kh = vcol >> 7, d = vcol & (HD - 1);
#pragma unroll
          for (int r = 0; r < 4; r++) {
            float v = acc[i][j][r] + bias;
            int tok = mg + r, bb2 = tok >> 11, n = tok & (SEQ - 1);
            Vn[((size_t)(bb2 * NKV + kh) * SEQ + n) * HD + d] = f2b(v);
          }
        }
      }
    }
  } else {
#pragma unroll
    for (int i = 0; i < 4; i++) {
      const int mg = m0 + wrow * 64 + i * 16 + lq * 4;
#pragma unroll
      for (int j = 0; j < NJ; j++) {
        const int ng = n0 + wcol * 64 + j * 16 + lm;
#pragma unroll
        for (int r = 0; r < 4; r++)
          Cf[(size_t)(mg + r) * Nn + ng] = acc[i][j][r];
      }
    }
  }
}

// ---------------- causal GQA flash attention (v5 + SCL2 pre-folded into Q) -----------
// Block p handles q-tiles {p, 31-p} (constant 33 work units). 512 blocks = 2/CU.
// Q arrives pre-scaled by (1/sqrt(128))*log2e from gemm0's epilogue -> softmax is
// exp2f(sv) directly.
__global__ __launch_bounds__(256, 2) void flash_kernel(
    const u16* __restrict__ Q, const u16* __restrict__ Kk,
    const u16* __restrict__ Vt, u16* __restrict__ Oo) {
  __shared__ u16 Kb[2][64 * 128];    // [kv][d-swizzled]
  __shared__ u16 Vb[2][144 * 64];    // [d][kv-permuted-swizzled]; row 128 = ones
  const int tid = threadIdx.x, lane = tid & 63, wave = tid >> 6;
  const int lm = lane & 15, lq = lane >> 4;
  const int p = blockIdx.x;                  // pair index 0..15
  const int h = blockIdx.y, b = blockIdx.z;
  const int q0A = p * 64, q0B = (31 - p) * 64;
  const int kvh = h >> 2;  // groups = H/KV = 4
  const u16* Qg = Q + (size_t)(b * NH + h) * SEQ * HD;
  const u16* Kg = Kk + (size_t)(b * NKV + kvh) * SEQ * HD;
  const u16* Vg = Vt + (size_t)(b * NKV + kvh) * HD * SEQ;  // [HD][SEQ]

  if (tid < 128) Vb[tid >> 6][128 * 64 + (tid & 63)] = 0x3F80;  // bf16 1.0 ones-row

  // loop-invariant Q fragments (B-operand: lane holds Q[q=lm][k=lq*8+j])
  bf16x8 qf[2][4];
#pragma unroll
  for (int qg = 0; qg < 2; qg++) {
    const int q0g = qg ? q0B : q0A;
    const u16* qrow = Qg + (size_t)(q0g + wave * 16 + lm) * HD;
#pragma unroll
    for (int kd = 0; kd < 4; kd++)
      qf[qg][kd] = *(const bf16x8*)&qrow[kd * 32 + lq * 8];
  }

  f32x4 oacc[2][8] = {};
  f32x4 oaccS[2] = {};             // ones-column: row-sums of P
  const int nIter = 32 - p;        // kv tiles needed by tile B

  // stage tile (64 kv) into buffer bufi: K 16KB contiguous, V 64-col slices
  auto stage = [&](int kv0, int bufi) {
    const char* kb = (const char*)(Kg + (size_t)kv0 * HD);
    char* kl = (char*)&Kb[bufi][0];
    const char* vbb = (const char*)(Vg + (size_t)kv0);
    char* vl = (char*)&Vb[bufi][0];
#pragma unroll
    for (int c = 0; c < 4; c++) {
      int ch = wave * 4 + c;
      glds16(kb + ch * 1024 + lane * 16, kl + ch * 1024);
      glds16(vbb + (size_t)(ch * 8 + (lane >> 3)) * (SEQ * 2) + (lane & 7) * 16,
             vl + ch * 1024);
    }
  };

  stage(0, 0);

  for (int t = 0; t < nIter; t++) {
    __syncthreads();                    // drains vmcnt -> tile t resident; closes reads of t-1
    if (t + 1 < nIter) stage((t + 1) * 64, (t + 1) & 1);  // async, hides behind compute
    const u16* Ks = &Kb[t & 1][0];
    const u16* Vs = &Vb[t & 1][0];
    const int kv0 = t * 64;
    const bool actA = (t <= p);  // tile A still needs this kv range

    auto run = [&](auto dualc) {
      constexpr bool DUAL = decltype(dualc)::value;
      // S^T tiles: lane holds S[q=lm][kv = nt*16 + lq*4 + r] per q-tile
      f32x4 sv[2][4] = {};
#pragma unroll
      for (int nt = 0; nt < 4; nt++)
#pragma unroll
        for (int kd = 0; kd < 4; kd++) {
          int g = kd * 4 + lq;
          int gpp = (g & 8) | ((g ^ lm) & 7);
          bf16x8 kf = *(const bf16x8*)&Ks[(nt * 16 + lm) * 128 + gpp * 8];
          sv[1][nt] = __builtin_amdgcn_mfma_f32_16x16x32_bf16(kf, qf[1][kd], sv[1][nt], 0, 0, 0);
          if constexpr (DUAL)
            sv[0][nt] = __builtin_amdgcn_mfma_f32_16x16x32_bf16(kf, qf[0][kd], sv[0][nt], 0, 0, 0);
        }

      // p = exp2(s) [scale pre-folded into Q]; perm-pack into x32 A-frags
      alignas(16) u32 pad[2][2][4];  // [qg][ks][dword]
      auto softmax = [&](int qg, int q0g) {
        const int base = q0g + wave * 16;
        if (kv0 + 63 > base) {  // tile straddles diagonal for this q-tile
          const int qrow = base + lm;
#pragma unroll
          for (int nt = 0; nt < 4; nt++) {
            float pv[4];
#pragma unroll
            for (int r = 0; r < 4; r++) {
              int kvg = kv0 + nt * 16 + lq * 4 + r;
              float e = exp2f(sv[qg][nt][r]);
              pv[r] = (kvg > qrow) ? 0.f : e;
            }
            pad[qg][nt & 1][(nt >> 1) * 2 + 0] = pack2bf(pv[0], pv[1]);
            pad[qg][nt & 1][(nt >> 1) * 2 + 1] = pack2bf(pv[2], pv[3]);
          }
        } else {
#pragma unroll
          for (int nt = 0; nt < 4; nt++) {
            float pv[4];
#pragma unroll
            for (int r = 0; r < 4; r++) pv[r] = exp2f(sv[qg][nt][r]);
            pad[qg][nt & 1][(nt >> 1) * 2 + 0] = pack2bf(pv[0], pv[1]);
            pad[qg][nt & 1][(nt >> 1) * 2 + 1] = pack2bf(pv[2], pv[3]);
          }
        }
      };
      softmax(1, q0B);
      if constexpr (DUAL) softmax(0, q0A);

      // O += P.V  (x32; B-frag = V^T[d][kv] slots, pre-permuted+swizzled)
#pragma unroll
      for (int ks = 0; ks < 2; ks++) {
        const int glp = (ks * 4 + lq) ^ (lm & 7);
        const bf16x8 pa1 = *(const bf16x8*)&pad[1][ks][0];
        const bf16x8 pa0 = *(const bf16x8*)&pad[0][ks][0];
#pragma unroll
        for (int dt = 0; dt < 8; dt++) {
          bf16x8 vf = *(const bf16x8*)&Vs[(dt * 16 + lm) * 64 + glp * 8];
          oacc[1][dt] = __builtin_amdgcn_mfma_f32_16x16x32_bf16(pa1, vf, oacc[1][dt], 0, 0, 0);
          if constexpr (DUAL)
            oacc[0][dt] = __builtin_amdgcn_mfma_f32_16x16x32_bf16(pa0, vf, oacc[0][dt], 0, 0, 0);
        }
        // ones-column -> row sums (col d=128 lives at lane lm==0)
        bf16x8 vf8 = *(const bf16x8*)&Vs[(128 + lm) * 64 + glp * 8];
        oaccS[1] = __builtin_amdgcn_mfma_f32_16x16x32_bf16(pa1, vf8, oaccS[1], 0, 0, 0);
        if constexpr (DUAL)
          oaccS[0] = __builtin_amdgcn_mfma_f32_16x16x32_bf16(pa0, vf8, oaccS[0], 0, 0, 0);
      }
    };
    if (actA) run(std::integral_constant<bool, true>{});
    else      run(std::integral_constant<bool, false>{});
  }

  // row m's sum sits at lane (m>>2)*16, reg m&3 of oaccS (C-layout col 128 = lm 0)
  u16* orow = Oo + (size_t)b * SEQ * CH + (size_t)h * HD;
#pragma unroll
  for (int qg = 0; qg < 2; qg++) {
    const int q0g = qg ? q0B : q0A;
    float inv[4];
#pragma unroll
    for (int r = 0; r < 4; r++) inv[r] = 1.0f / __shfl(oaccS[qg][r], lq * 16);
    const int qrow_base = q0g + wave * 16 + lq * 4;
#pragma unroll
    for (int dt = 0; dt < 8; dt++)
#pragma unroll
      for (int r = 0; r < 4; r++)
        orow[(size_t)(qrow_base + r) * CH + dt * 16 + lm] = f2b(oacc[qg][dt][r] * inv[r]);
  }
}

extern "C" void kernel_launch(void* const* d_in, const int* in_sizes, int n_in,
                              void* d_out, int out_size, void* d_ws, size_t ws_size,
                              hipStream_t stream) {
  const float* x = (const float*)d_in[0];
  const int* pos = (const int*)d_in[1];
  const float* Wq = (const float*)d_in[2];
  const float* bq = (const float*)d_in[3];
  const float* Wk = (const float*)d_in[4];
  const float* bk = (const float*)d_in[5];
  const float* Wv = (const float*)d_in[6];
  const float* bv = (const float*)d_in[7];
  const float* Wo = (const float*)d_in[8];
  float* out = (float*)d_out;

  char* ws = (char*)d_ws;
  u16* xb = (u16*)ws;    ws += (size_t)BB * SEQ * CH * 2;        // 16.8 MB
  u16* wqkvt = (u16*)ws; ws += (size_t)QKVC * CH * 2;            // 12.6 MB  (3072 x 2048, n-major)
  u16* wot = (u16*)ws;   ws += (size_t)CH * CH * 2;              // 8.4 MB
  u16* qr = (u16*)ws;    ws += (size_t)BB * NH * SEQ * HD * 2;   // 16.8 MB
  u16* kr = (u16*)ws;    ws += (size_t)BB * NKV * SEQ * HD * 2;  // 4.2 MB
  u16* vn = (u16*)ws;    ws += (size_t)BB * NKV * SEQ * HD * 2;  // 4.2 MB
  u16* vt = (u16*)ws;    ws += (size_t)BB * NKV * SEQ * HD * 2;  // 4.2 MB
  u16* ao = (u16*)ws;    ws += (size_t)BB * SEQ * CH * 2;        // 16.8 MB

  static int attr_done = 0;
  if (!attr_done) {
    hipFuncSetAttribute(reinterpret_cast<const void*>(gemm4w_kernel<0>),
                        hipFuncAttributeMaxDynamicSharedMemorySize, 131072);
    hipFuncSetAttribute(reinterpret_cast<const void*>(gemm4w_kernel<1>),
                        hipFuncAttributeMaxDynamicSharedMemorySize, 131072);
    attr_done = 1;
  }

  prep_kernel<<<dim3(32, 32, 5), 256, 0, stream>>>(x, xb, Wq, Wk, Wv, Wo, wqkvt, wot);
  gemm4w_kernel<0><<<dim3(32, 16), 256, 65536, stream>>>(
      xb, wqkvt, qr, kr, (float*)nullptr, vn, bq, bk, bv, pos, BB * SEQ, QKVC, CH);
  vtrans_kernel<<<dim3(SEQ / 64, HD / 64, BB * NKV), 256, 0, stream>>>(vn, vt);
  flash_kernel<<<dim3(16, NH, BB), 256, 0, stream>>>(qr, kr, vt, ao);
  gemm4w_kernel<1><<<dim3(32, 16), 256, 49152, stream>>>(
      ao, wot, nullptr, nullptr, out, nullptr, nullptr, nullptr, nullptr, nullptr,
      BB * SEQ, CH, CH);
}